// Round 5
// baseline (254.187 us; speedup 1.0000x reference)
//
#include <hip/hip_runtime.h>
#include <stdint.h>

#define TT 1024
#define AL 0.05f
#define OM 0.95f
#define STRD 408   // padded [c][.] row stride
#define LOG2E 1.4426950408889634f

typedef short s4v __attribute__((ext_vector_type(4)));
typedef short s8v __attribute__((ext_vector_type(8)));
typedef float f4v __attribute__((ext_vector_type(4)));
typedef float f16v __attribute__((ext_vector_type(16)));
typedef int   i2v __attribute__((ext_vector_type(2)));

#define MF32(a,b,c) __builtin_amdgcn_mfma_f32_32x32x16_bf16(a,b,c,0,0,0)
#define MF16(a,b,c) __builtin_amdgcn_mfma_f32_16x16x32_bf16(a,b,c,0,0,0)

#if __has_builtin(__builtin_amdgcn_exp2f)
#define E2(x) __builtin_amdgcn_exp2f(x)
#else
#define E2(x) exp2f(x)
#endif

__device__ __forceinline__ uint16_t f2bf(float f){ union{float f;uint32_t i;}t; t.f=f; return (uint16_t)((t.i + 0x7fffu + ((t.i>>16)&1u))>>16); }
__device__ __forceinline__ float bf2f(uint16_t h){ union{uint32_t i;float f;}t; t.i=((uint32_t)h)<<16; return t.f; }
__device__ __forceinline__ float bfLO(uint32_t u){ union{uint32_t i;float f;}t; t.i=u<<16; return t.f; }
__device__ __forceinline__ float bfHI(uint32_t u){ union{uint32_t i;float f;}t; t.i=u&0xffff0000u; return t.f; }
// packed f32->bf16 (RNE, same semantics as f2bf), 1 inst per pair
__device__ __forceinline__ uint32_t cvtpk(float lo, float hi){ uint32_t r; asm("v_cvt_pk_bf16_f32 %0, %1, %2" : "=v"(r) : "v"(lo), "v"(hi)); return r; }
// exchange hi-half(x) <-> lo-half(y) across the lane32 boundary
__device__ __forceinline__ void pl32swap(uint32_t &x, uint32_t &y){
#if __has_builtin(__builtin_amdgcn_permlane32_swap)
  i2v rr = __builtin_amdgcn_permlane32_swap((int)x, (int)y, false, false);
  x = (uint32_t)rr.x; y = (uint32_t)rr.y;
#else
  asm("v_permlane32_swap_b32 %0, %1" : "+v"(x), "+v"(y));
#endif
}
// tanh(x) = 1 - 2/(1+e^{2x}) : 5 VALU ops vs libm tanhf
__device__ __forceinline__ float ftanh(float x){ float t = E2(2.885390081777927f*x); return __builtin_fmaf(-2.f, __builtin_amdgcn_rcpf(1.f + t), 1.f); }
__device__ __forceinline__ s8v ld8(const uint16_t* p){ return *(const s8v*)p; }
__device__ __forceinline__ s8v ld8u(const uint16_t* p){
  s4v lo = *(const s4v*)p; s4v hi = *(const s4v*)(p+4);
  return __builtin_shufflevector(lo, hi, 0,1,2,3,4,5,6,7);
}
#define ROWF(e2) (((e2)&3) + 8*((e2)>>2) + 4*h2)
// bank-conflict swizzle for [v][32] u16 buffers: XOR u16-idx bits 3-5 with v&7.
#define VXA(row,off) ((((row)<<5) + (off)) ^ (((row)&7)<<3))

// staging buffer for output transpose
__device__ __align__(16) float gStage[32*12*12800];

// S map (u16), total 81568 = 163.1 KB
#define X1S 0
#define X2S 12800
#define XCV 25600
#define PBA 38656
#define HCV 54656
#define GCV 67712
#define RINV 80768
#define CINV 81168

__global__ __launch_bounds__(TT) void dymix(
    const float* __restrict__ x,
    const float* __restrict__ w1, const float* __restrict__ b1,
    const float* __restrict__ w2, const float* __restrict__ b2,
    const float* __restrict__ wm1, const float* __restrict__ bm1,
    const float* __restrict__ wm2, const float* __restrict__ bm2)
{
  __shared__ __align__(16) uint16_t S[81568];

  const int blk = blockIdx.x;
  const int xcd = blk & 7, slot = blk >> 3;    // group 12 l-blocks of each n per XCD
  const int n = xcd*4 + slot/12;
  const int l = slot - (slot/12)*12;
  const int t = threadIdx.x;
  const int wv = t >> 6;        // 0..15
  const int lane = t & 63;
  const int q  = lane >> 4;
  const int r  = lane & 15;
  const int h2 = lane >> 5;
  const int m32 = lane & 31;
  const long xbase = (long)n*153600 + l;

  // ---------- Phase 0: stage X -> XCV [c][408] ----------
  for (int i = t; i < 12800; i += TT) {
    int c = i / 400, v = i - c*400;
    S[XCV + c*STRD + v] = f2bf(x[xbase + (long)i*12]);
  }
  __syncthreads();

  // ---------- Phase L prep: XT (swizzled [v][32]) + lin weights into PBA ----------
  for (int i = t; i < 12800; i += TT) { int v = i>>5, c = i&31; S[PBA + VXA(v,c)] = S[XCV + c*STRD + v]; }
  for (int i = t; i < 1024; i += TT) {
    int o = i>>5, c = i&31;
    S[PBA + 12800 + o*40 + c] = f2bf(w1[i]);
    S[PBA + 14080 + o*40 + c] = f2bf(w2[i]);
  }
  if (t < 32) { ((float*)(S+PBA+15360))[t] = b1[t]; ((float*)(S+PBA+15424))[t] = b2[t]; }
  __syncthreads();

  // ---------- Phase L: x1 = log2e*tanh(W1 X + b1), x2 = tanh(W2 X + b2) -> swizzled [v][32] ----------
  #pragma unroll
  for (int j = 0; j < 2; ++j) {
    int u = wv + 16*j;
    if (u < 24) {
      int nt = u >> 1, li = u & 1;
      const uint16_t* W = S + PBA + 12800 + li*1280;
      const float* bfp = (const float*)(S + PBA + 15360 + li*64);
      uint16_t* dst = S + (li ? X2S : X1S);
      const float osc = li ? 1.f : LOG2E;
      f16v z = {};
      #pragma unroll
      for (int kk = 0; kk < 2; ++kk) {
        s8v a = ld8(W + m32*40 + kk*16 + h2*8);
        s8v b = ld8(S + PBA + VXA(nt*32 + m32, kk*16 + h2*8));
        z = MF32(a, b, z);
      }
      int v = nt*32 + m32;
      #pragma unroll
      for (int g = 0; g < 4; ++g) {
        float p0 = ftanh(z[4*g+0] + bfp[8*g+4*h2+0]) * osc;
        float p1 = ftanh(z[4*g+1] + bfp[8*g+4*h2+1]) * osc;
        float p2 = ftanh(z[4*g+2] + bfp[8*g+4*h2+2]) * osc;
        float p3 = ftanh(z[4*g+3] + bfp[8*g+4*h2+3]) * osc;
        uint2 d; d.x = cvtpk(p0,p1); d.y = cvtpk(p2,p3);
        *(uint2*)(dst + VXA(v, 8*g + 4*h2)) = d;
      }
    } else if (u < 28) {
      int li = (u-24)>>1, mt = u&1;
      const uint16_t* W = S + PBA + 12800 + li*1280;
      const float* bfp = (const float*)(S + PBA + 15360 + li*64);
      uint16_t* dst = S + (li ? X2S : X1S);
      const float osc = li ? 1.f : LOG2E;
      s8v a = ld8(W + (mt*16 + r)*40 + q*8);
      s8v b = ld8(S + PBA + VXA(384 + r, q*8));
      f4v z4 = {}; z4 = MF16(a, b, z4);
      float p0 = ftanh(z4[0] + bfp[mt*16+q*4+0]) * osc;
      float p1 = ftanh(z4[1] + bfp[mt*16+q*4+1]) * osc;
      float p2 = ftanh(z4[2] + bfp[mt*16+q*4+2]) * osc;
      float p3 = ftanh(z4[3] + bfp[mt*16+q*4+3]) * osc;
      uint2 d; d.x = cvtpk(p0,p1); d.y = cvtpk(p2,p3);
      *(uint2*)(dst + VXA(384 + r, mt*16 + q*4)) = d;
    }
  }
  // preload MLP X b-frags from XT (XT dies when diffusion starts)
  s8v xf0, xf1, xft;
  {
    int m0 = (wv < 12) ? wv : 0;
    xf0 = ld8(S + PBA + VXA(m0*32 + m32, h2*8));
    xf1 = ld8(S + PBA + VXA(m0*32 + m32, 16 + h2*8));
    xft = ld8(S + PBA + VXA(384 + r, q*8));
  }
  __syncthreads();

  // ---------- Stats: rowsum/colsum of exp2(A') ----------
  float* rsf = (float*)(S + HCV);
  float* csf = rsf + 400;
  for (int i = t; i < 400; i += TT) csf[i] = 0.f;
  __syncthreads();
  {
    s8v av[2]; f4v rac[2] = {{},{}};
    #pragma unroll
    for (int jj = 0; jj < 2; ++jj) { int vt = wv + 16*jj; if (vt < 25) av[jj] = ld8(S + X1S + VXA(vt*16 + r, q*8)); }
    s8v bnx = ld8(S + X2S + VXA(r, q*8));   // wt=0 prefetch
    for (int wt = 0; wt < 25; ++wt) {
      s8v b = bnx;
      if (wt < 24) bnx = ld8(S + X2S + VXA((wt+1)*16 + r, q*8));
      float cp = 0.f;
      #pragma unroll
      for (int jj = 0; jj < 2; ++jj) {
        int vt = wv + 16*jj;
        if (vt < 25) {
          f4v z = {}; z = MF16(av[jj], b, z);
          #pragma unroll
          for (int e = 0; e < 4; ++e) { float ev = E2(z[e]); rac[jj][e] += ev; cp += ev; }
        }
      }
      cp += __shfl_xor(cp, 16); cp += __shfl_xor(cp, 32);
      if (q == 0) atomicAdd(&csf[wt*16 + r], cp);
    }
    #pragma unroll
    for (int jj = 0; jj < 2; ++jj) {
      int vt = wv + 16*jj;
      if (vt < 25) {
        #pragma unroll
        for (int e = 0; e < 4; ++e) {
          float s = rac[jj][e];
          s += __shfl_xor(s,1); s += __shfl_xor(s,2); s += __shfl_xor(s,4); s += __shfl_xor(s,8);
          if (r == 0) rsf[vt*16 + q*4 + e] = s;
        }
      }
    }
  }
  __syncthreads();
  for (int i = t; i < 400; i += TT) { S[RINV + i] = f2bf(1.f/rsf[i]); S[CINV + i] = f2bf(1.f/csf[i]); }
  __syncthreads();

  // ---------- Diffusion: wave-private producer/consumer units, zero intra-step barriers.
  // Round-5 restructure: LOOP FISSION per unit. Main units get a STORE-FREE 13-sb loop
  // (the tail unit's P-stores in the old fused body alias-fenced every ds_read for all
  // waves, blocking invariant hoisting and cross-iteration pipelining). Tail units get
  // their own loop. Per-unit locals are loop-scoped (64-VGPR regime: no long live ranges).
  // Reordering per-wave work is legal: units are wave-private, no intra-step barriers.
  f16v acc[2];
  for (int step = 0; step < 2; ++step) {
    { f16v zv = {}; acc[0]=zv; acc[1]=zv; }
    const uint16_t* AH = S + (step ? HCV : XCV);
    const uint16_t* AG = S + (step ? GCV : XCV);
    uint16_t* P0 = S + (step ? 40256 : PBA);
    uint16_t* P1 = S + (step ? XCV : 53056);
    #pragma unroll
    for (int jj = 0; jj < 2; ++jj) {
      int g = wv + 16*jj;
      if (g >= 26) continue;
      int chain = (g < 13) ? 0 : 1;
      int uu = g - 13*chain;
      const uint16_t* sa = S + (chain ? X2S : X1S);   // m-operand: v-slab rows
      const uint16_t* sb2 = S + (chain ? X1S : X2S);  // n-operand: w-tile rows (sb-invariant)
      const int scl = chain ? CINV : RINV;
      const uint16_t* Acv = chain ? AG : AH;
      if (uu < 12) {
        // ---- main unit: store-free loop; compiler pipelines ds_reads across iterations ----
        s8v hbA = ld8(sb2 + VXA(uu*32 + m32, h2*8));
        s8v hbB = ld8(sb2 + VXA(uu*32 + m32, 16 + h2*8));
        f16v av = acc[jj];
        #pragma unroll 2
        for (int sb = 0; sb < 12; ++sb) {
          const int vbase = sb*32;
          s8v a0 = ld8(sa + VXA(vbase + m32, h2*8));
          s8v a1 = ld8(sa + VXA(vbase + m32, 16 + h2*8));
          f16v z = {}; z = MF32(a0, hbA, z); z = MF32(a1, hbB, z);
          #pragma unroll
          for (int k = 0; k < 2; ++k) {
            const uint16_t* spt = S + scl + vbase + 16*k + 4*h2;
            uint32_t sAB = *(const uint32_t*)(spt);
            uint32_t sCD = *(const uint32_t*)(spt + 2);
            uint32_t sEF = *(const uint32_t*)(spt + 8);
            uint32_t sGH = *(const uint32_t*)(spt + 10);
            uint32_t C0 = cvtpk(E2(z[8*k+0])*bfLO(sAB), E2(z[8*k+1])*bfHI(sAB));
            uint32_t C1 = cvtpk(E2(z[8*k+2])*bfLO(sCD), E2(z[8*k+3])*bfHI(sCD));
            uint32_t C2 = cvtpk(E2(z[8*k+4])*bfLO(sEF), E2(z[8*k+5])*bfHI(sEF));
            uint32_t C3 = cvtpk(E2(z[8*k+6])*bfLO(sGH), E2(z[8*k+7])*bfHI(sGH));
            pl32swap(C0, C2);   // C0 -> dw0, C2 -> dw2
            pl32swap(C1, C3);   // C1 -> dw1, C3 -> dw3
            union { uint32_t d[4]; s8v v8; } F;
            F.d[0] = C0; F.d[1] = C1; F.d[2] = C2; F.d[3] = C3;
            s8v ga = ld8(Acv + m32*STRD + vbase + k*16 + h2*8);
            av = MF32(ga, F.v8, av);
          }
        }
        { // peeled sb = 12 (k=0 only: rows 400..415 are garbage, never consumed)
          const int vbase = 384;
          s8v a0 = ld8(sa + VXA(vbase + m32, h2*8));
          s8v a1 = ld8(sa + VXA(vbase + m32, 16 + h2*8));
          f16v z = {}; z = MF32(a0, hbA, z); z = MF32(a1, hbB, z);
          const uint16_t* spt = S + scl + vbase + 4*h2;
          uint32_t sAB = *(const uint32_t*)(spt);
          uint32_t sCD = *(const uint32_t*)(spt + 2);
          uint32_t sEF = *(const uint32_t*)(spt + 8);
          uint32_t sGH = *(const uint32_t*)(spt + 10);
          uint32_t C0 = cvtpk(E2(z[0])*bfLO(sAB), E2(z[1])*bfHI(sAB));
          uint32_t C1 = cvtpk(E2(z[2])*bfLO(sCD), E2(z[3])*bfHI(sCD));
          uint32_t C2 = cvtpk(E2(z[4])*bfLO(sEF), E2(z[5])*bfHI(sEF));
          uint32_t C3 = cvtpk(E2(z[6])*bfLO(sGH), E2(z[7])*bfHI(sGH));
          pl32swap(C0, C2);
          pl32swap(C1, C3);
          union { uint32_t d[4]; s8v v8; } F;
          F.d[0] = C0; F.d[1] = C1; F.d[2] = C2; F.d[3] = C3;
          s8v ga = ld8(Acv + m32*STRD + vbase + h2*8);
          av = MF32(ga, F.v8, av);
        }
        acc[jj] = av;
      } else {
        // ---- tail unit (rows 384..399): LDS P round-trip, own loop ----
        uint16_t* P = chain ? P1 : P0;
        s8v hbT = ld8(sb2 + VXA(384 + r, q*8));
        f16v av = acc[jj];
        for (int sb = 0; sb < 13; ++sb) {
          const int vbase = sb*32;
          const bool lastsb = (sb == 12);
          int ctmax = lastsb ? 1 : 2;
          for (int ct = 0; ct < ctmax; ++ct) {
            s8v a = ld8(sa + VXA(vbase + ct*16 + r, q*8));
            f4v z4 = {}; z4 = MF16(a, hbT, z4);
            float p0 = E2(z4[0]) * bf2f(S[scl + vbase + ct*16 + q*4 + 0]);
            float p1 = E2(z4[1]) * bf2f(S[scl + vbase + ct*16 + q*4 + 1]);
            float p2 = E2(z4[2]) * bf2f(S[scl + vbase + ct*16 + q*4 + 2]);
            float p3 = E2(z4[3]) * bf2f(S[scl + vbase + ct*16 + q*4 + 3]);
            uint2 d; d.x = cvtpk(p0,p1); d.y = cvtpk(p2,p3);
            *(uint2*)(P + (384 + r)*36 + ct*16 + q*4) = d;
          }
          if (lastsb && lane < 16) {
            uint2 z0 = {0u,0u};
            uint16_t* pz = P + (384 + lane)*36 + 16;
            *(uint2*)(pz) = z0; *(uint2*)(pz+4) = z0; *(uint2*)(pz+8) = z0; *(uint2*)(pz+12) = z0;
          }
          #pragma unroll
          for (int mt2 = 0; mt2 < 2; ++mt2) {
            int koff = (lastsb && q >= 2) ? 0 : q*8;   // pad cols never written — NaN guard (×0 in P)
            s8v a = ld8(Acv + (mt2*16 + r)*STRD + vbase + koff);
            s8v b = ld8u(P + (384 + r)*36 + q*8);
            f4v c4 = { av[4*mt2+0], av[4*mt2+1], av[4*mt2+2], av[4*mt2+3] };
            c4 = MF16(a, b, c4);
            av[4*mt2+0]=c4[0]; av[4*mt2+1]=c4[1]; av[4*mt2+2]=c4[2]; av[4*mt2+3]=c4[3];
          }
        }
        acc[jj] = av;
      }
    } // jj
    __syncthreads();
    if (step == 0) {
      // epilogue: H1/G1 = AL*X + OM*acc -> HCV/GCV [c][408]
      #pragma unroll
      for (int jj = 0; jj < 2; ++jj) {
        int g = wv + 16*jj;
        if (g >= 26) continue;
        int chain = (g < 13) ? 0 : 1;
        int uu = g - 13*chain;
        uint16_t* dst = S + (chain ? GCV : HCV);
        if (uu < 12) {
          int w = uu*32 + m32;
          #pragma unroll
          for (int e2 = 0; e2 < 16; ++e2) {
            int c = ROWF(e2);
            dst[c*STRD + w] = f2bf(AL*bf2f(S[XCV + c*STRD + w]) + OM*acc[jj][e2]);
          }
        } else {
          int w = 384 + r;
          #pragma unroll
          for (int mt2 = 0; mt2 < 2; ++mt2)
            #pragma unroll
            for (int e = 0; e < 4; ++e) {
              int c = mt2*16 + q*4 + e;
              dst[c*STRD + w] = f2bf(AL*bf2f(S[XCV + c*STRD + w]) + OM*acc[jj][4*mt2+e]);
            }
        }
      }
      __syncthreads();
    }
  } // step

  // ---------- MLP prep: features to swizzled [v][32]; weights folded into HCV ----------
  for (int i = t; i < 12800; i += TT) {
    int v = i >> 5, c = i & 31;
    int d = VXA(v, c);
    S[X1S + d] = S[HCV + c*STRD + v];   // H1
    S[X2S + d] = S[GCV + c*STRD + v];   // G1
  }
  #pragma unroll
  for (int jj = 0; jj < 2; ++jj) {
    int g = wv + 16*jj;
    if (g >= 26) continue;
    int chain = (g < 13) ? 0 : 1;
    int uu = g - 13*chain;
    uint16_t* dst = S + (chain ? PBA : XCV);   // H2' -> XCV, G2' -> PBA  (as swizzled [v][32])
    if (uu < 12) {
      int w = uu*32 + m32;
      #pragma unroll
      for (int gg = 0; gg < 4; ++gg) {
        uint2 d;
        d.x = cvtpk(OM*acc[jj][4*gg+0], OM*acc[jj][4*gg+1]);
        d.y = cvtpk(OM*acc[jj][4*gg+2], OM*acc[jj][4*gg+3]);
        *(uint2*)(dst + VXA(w, 8*gg + 4*h2)) = d;
      }
    } else {
      int w = 384 + r;
      #pragma unroll
      for (int mt2 = 0; mt2 < 2; ++mt2) {
        uint2 d;
        d.x = cvtpk(OM*acc[jj][4*mt2+0], OM*acc[jj][4*mt2+1]);
        d.y = cvtpk(OM*acc[jj][4*mt2+2], OM*acc[jj][4*mt2+3]);
        *(uint2*)(dst + VXA(w, mt2*16 + q*4)) = d;
      }
    }
  }
  __syncthreads();
  for (int i = t; i < 1024; i += TT) {
    int o = i >> 5, c = i & 31;
    float h2w = wm1[o*96 + 64 + c], g2w = wm2[o*96 + 64 + c];
    S[HCV +        o*40 + c] = f2bf(wm1[o*96 + c] + wm2[o*96 + c] + AL*(h2w + g2w));
    S[HCV + 1280 + o*40 + c] = f2bf(wm1[o*96 + 32 + c]);
    S[HCV + 2560 + o*40 + c] = f2bf(h2w);
    S[HCV + 3840 + o*40 + c] = f2bf(wm2[o*96 + 32 + c]);
    S[HCV + 5120 + o*40 + c] = f2bf(g2w);
  }
  if (t < 32) ((float*)(S + HCV + 6400))[t] = bm1[t] + bm2[t];
  __syncthreads();

  // ---------- MLP + coalesced staged store to gStage[n][l][o][v] ----------
  {
    const float* boF = (const float*)(S + HCV + 6400);
    float* oSl = gStage + (long)(n*12 + l)*12800;
    const int fb[5] = { 0, X1S, XCV, X2S, PBA };   // X(regs), H1, H2', G1, G2'
    int m = wv;
    if (m < 12) {
      f16v z = {};
      #pragma unroll
      for (int p = 0; p < 5; ++p) {
        #pragma unroll
        for (int kk = 0; kk < 2; ++kk) {
          s8v a = ld8(S + HCV + p*1280 + m32*40 + kk*16 + h2*8);
          s8v b;
          if (p == 0) b = kk ? xf1 : xf0;
          else        b = ld8(S + fb[p] + VXA(m*32 + m32, kk*16 + h2*8));
          z = MF32(a, b, z);
        }
      }
      int v = m*32 + m32;
      #pragma unroll
      for (int e2 = 0; e2 < 16; ++e2) {
        int o = ROWF(e2);
        oSl[o*400 + v] = z[e2] + boF[o];
      }
    } else if (m < 14) {
      int mt = m - 12;
      f4v z4 = {};
      #pragma unroll
      for (int p = 0; p < 5; ++p) {
        s8v a = ld8(S + HCV + p*1280 + (mt*16 + r)*40 + q*8);
        s8v b = (p == 0) ? xft : ld8(S + fb[p] + VXA(384 + r, q*8));
        z4 = MF16(a, b, z4);
      }
      #pragma unroll
      for (int e = 0; e < 4; ++e) {
        int o = mt*16 + q*4 + e;
        oSl[o*400 + 384 + r] = z4[e] + boF[o];
      }
    }
  }
}

// Plain transpose kernel: gStage[n][l][o][v] -> out[n][o][v][l] (both sides coalesced)
__global__ __launch_bounds__(256) void finT(float* __restrict__ out) {
  int idx = blockIdx.x*256 + threadIdx.x;      // n*12800 + ov
  int n = idx / 12800, ov = idx - n*12800;
  const float* src = gStage + (long)n*153600 + ov;
  float vals[12];
  #pragma unroll
  for (int l = 0; l < 12; ++l) vals[l] = src[(long)l*12800];
  float4* dst = (float4*)(out + (long)idx*12);
  dst[0] = make_float4(vals[0],vals[1],vals[2],vals[3]);
  dst[1] = make_float4(vals[4],vals[5],vals[6],vals[7]);
  dst[2] = make_float4(vals[8],vals[9],vals[10],vals[11]);
}

extern "C" void kernel_launch(void* const* d_in, const int* in_sizes, int n_in,
                              void* d_out, int out_size, void* d_ws, size_t ws_size,
                              hipStream_t stream) {
  (void)in_sizes; (void)n_in; (void)out_size; (void)d_ws; (void)ws_size;
  dymix<<<dim3(384), dim3(TT), 0, stream>>>(
      (const float*)d_in[0],
      (const float*)d_in[1], (const float*)d_in[2],
      (const float*)d_in[3], (const float*)d_in[4],
      (const float*)d_in[5], (const float*)d_in[6],
      (const float*)d_in[7], (const float*)d_in[8]);
  finT<<<dim3(1600), dim3(256), 0, stream>>>((float*)d_out);
}

// Round 6
// 231.451 us; speedup vs baseline: 1.0982x; 1.0982x over previous
//
#include <hip/hip_runtime.h>
#include <stdint.h>

#define TT 1024
#define AL 0.05f
#define OM 0.95f
#define STRD 408   // padded [c][.] row stride
#define LOG2E 1.4426950408889634f

typedef short s4v __attribute__((ext_vector_type(4)));
typedef short s8v __attribute__((ext_vector_type(8)));
typedef float f4v __attribute__((ext_vector_type(4)));
typedef float f16v __attribute__((ext_vector_type(16)));
typedef int   i2v __attribute__((ext_vector_type(2)));

#define MF32(a,b,c) __builtin_amdgcn_mfma_f32_32x32x16_bf16(a,b,c,0,0,0)
#define MF16(a,b,c) __builtin_amdgcn_mfma_f32_16x16x32_bf16(a,b,c,0,0,0)

#if __has_builtin(__builtin_amdgcn_exp2f)
#define E2(x) __builtin_amdgcn_exp2f(x)
#else
#define E2(x) exp2f(x)
#endif

__device__ __forceinline__ uint16_t f2bf(float f){ union{float f;uint32_t i;}t; t.f=f; return (uint16_t)((t.i + 0x7fffu + ((t.i>>16)&1u))>>16); }
__device__ __forceinline__ float bf2f(uint16_t h){ union{uint32_t i;float f;}t; t.i=((uint32_t)h)<<16; return t.f; }
__device__ __forceinline__ float bfLO(uint32_t u){ union{uint32_t i;float f;}t; t.i=u<<16; return t.f; }
__device__ __forceinline__ float bfHI(uint32_t u){ union{uint32_t i;float f;}t; t.i=u&0xffff0000u; return t.f; }
// packed f32->bf16 (RNE, same semantics as f2bf), 1 inst per pair
__device__ __forceinline__ uint32_t cvtpk(float lo, float hi){ uint32_t r; asm("v_cvt_pk_bf16_f32 %0, %1, %2" : "=v"(r) : "v"(lo), "v"(hi)); return r; }
// exchange hi-half(x) <-> lo-half(y) across the lane32 boundary
__device__ __forceinline__ void pl32swap(uint32_t &x, uint32_t &y){
#if __has_builtin(__builtin_amdgcn_permlane32_swap)
  i2v rr = __builtin_amdgcn_permlane32_swap((int)x, (int)y, false, false);
  x = (uint32_t)rr.x; y = (uint32_t)rr.y;
#else
  asm("v_permlane32_swap_b32 %0, %1" : "+v"(x), "+v"(y));
#endif
}
// tanh(x) = 1 - 2/(1+e^{2x}) : 5 VALU ops vs libm tanhf
__device__ __forceinline__ float ftanh(float x){ float t = E2(2.885390081777927f*x); return __builtin_fmaf(-2.f, __builtin_amdgcn_rcpf(1.f + t), 1.f); }
__device__ __forceinline__ s8v ld8(const uint16_t* p){ return *(const s8v*)p; }
#define ROWF(e2) (((e2)&3) + 8*((e2)>>2) + 4*h2)
// bank-conflict swizzle for [v][32] u16 buffers: XOR u16-idx bits 3-5 with v&7.
#define VXA(row,off) ((((row)<<5) + (off)) ^ (((row)&7)<<3))

// staging buffer for output transpose
__device__ __align__(16) float gStage[32*12*12800];

// S map (u16), total 81568 = 163.1 KB
#define X1S 0
#define X2S 12800
#define XCV 25600
#define PBA 38656
#define HCV 54656
#define GCV 67712
#define RINV 80768
#define CINV 81168

__global__ __launch_bounds__(TT) void dymix(
    const float* __restrict__ x,
    const float* __restrict__ w1, const float* __restrict__ b1,
    const float* __restrict__ w2, const float* __restrict__ b2,
    const float* __restrict__ wm1, const float* __restrict__ bm1,
    const float* __restrict__ wm2, const float* __restrict__ bm2)
{
  __shared__ __align__(16) uint16_t S[81568];

  const int blk = blockIdx.x;
  const int xcd = blk & 7, slot = blk >> 3;    // group 12 l-blocks of each n per XCD
  const int n = xcd*4 + slot/12;
  const int l = slot - (slot/12)*12;
  const int t = threadIdx.x;
  const int wv = t >> 6;        // 0..15
  const int lane = t & 63;
  const int q  = lane >> 4;
  const int r  = lane & 15;
  const int h2 = lane >> 5;
  const int m32 = lane & 31;
  const long xbase = (long)n*153600 + l;

  // ---------- Phase 0: stage X -> XCV [c][408] ----------
  for (int i = t; i < 12800; i += TT) {
    int c = i / 400, v = i - c*400;
    S[XCV + c*STRD + v] = f2bf(x[xbase + (long)i*12]);
  }
  __syncthreads();

  // ---------- Phase L prep: XT (swizzled [v][32]) + lin weights into PBA ----------
  for (int i = t; i < 12800; i += TT) { int v = i>>5, c = i&31; S[PBA + VXA(v,c)] = S[XCV + c*STRD + v]; }
  for (int i = t; i < 1024; i += TT) {
    int o = i>>5, c = i&31;
    S[PBA + 12800 + o*40 + c] = f2bf(w1[i]);
    S[PBA + 14080 + o*40 + c] = f2bf(w2[i]);
  }
  if (t < 32) { ((float*)(S+PBA+15360))[t] = b1[t]; ((float*)(S+PBA+15424))[t] = b2[t]; }
  __syncthreads();

  // ---------- Phase L: x1 = log2e*tanh(W1 X + b1), x2 = tanh(W2 X + b2) -> swizzled [v][32] ----------
  #pragma unroll
  for (int j = 0; j < 2; ++j) {
    int u = wv + 16*j;
    if (u < 24) {
      int nt = u >> 1, li = u & 1;
      const uint16_t* W = S + PBA + 12800 + li*1280;
      const float* bfp = (const float*)(S + PBA + 15360 + li*64);
      uint16_t* dst = S + (li ? X2S : X1S);
      const float osc = li ? 1.f : LOG2E;
      f16v z = {};
      #pragma unroll
      for (int kk = 0; kk < 2; ++kk) {
        s8v a = ld8(W + m32*40 + kk*16 + h2*8);
        s8v b = ld8(S + PBA + VXA(nt*32 + m32, kk*16 + h2*8));
        z = MF32(a, b, z);
      }
      int v = nt*32 + m32;
      #pragma unroll
      for (int g = 0; g < 4; ++g) {
        float p0 = ftanh(z[4*g+0] + bfp[8*g+4*h2+0]) * osc;
        float p1 = ftanh(z[4*g+1] + bfp[8*g+4*h2+1]) * osc;
        float p2 = ftanh(z[4*g+2] + bfp[8*g+4*h2+2]) * osc;
        float p3 = ftanh(z[4*g+3] + bfp[8*g+4*h2+3]) * osc;
        uint2 d; d.x = cvtpk(p0,p1); d.y = cvtpk(p2,p3);
        *(uint2*)(dst + VXA(v, 8*g + 4*h2)) = d;
      }
    } else if (u < 28) {
      int li = (u-24)>>1, mt = u&1;
      const uint16_t* W = S + PBA + 12800 + li*1280;
      const float* bfp = (const float*)(S + PBA + 15360 + li*64);
      uint16_t* dst = S + (li ? X2S : X1S);
      const float osc = li ? 1.f : LOG2E;
      s8v a = ld8(W + (mt*16 + r)*40 + q*8);
      s8v b = ld8(S + PBA + VXA(384 + r, q*8));
      f4v z4 = {}; z4 = MF16(a, b, z4);
      float p0 = ftanh(z4[0] + bfp[mt*16+q*4+0]) * osc;
      float p1 = ftanh(z4[1] + bfp[mt*16+q*4+1]) * osc;
      float p2 = ftanh(z4[2] + bfp[mt*16+q*4+2]) * osc;
      float p3 = ftanh(z4[3] + bfp[mt*16+q*4+3]) * osc;
      uint2 d; d.x = cvtpk(p0,p1); d.y = cvtpk(p2,p3);
      *(uint2*)(dst + VXA(384 + r, mt*16 + q*4)) = d;
    }
  }
  // preload MLP X b-frags from XT (XT dies when diffusion starts)
  s8v xf0, xf1, xft;
  {
    int m0 = (wv < 12) ? wv : 0;
    xf0 = ld8(S + PBA + VXA(m0*32 + m32, h2*8));
    xf1 = ld8(S + PBA + VXA(m0*32 + m32, 16 + h2*8));
    xft = ld8(S + PBA + VXA(384 + r, q*8));
  }
  __syncthreads();

  // ---------- Stats: rowsum/colsum of exp2(A') ----------
  float* rsf = (float*)(S + HCV);
  float* csf = rsf + 400;
  for (int i = t; i < 400; i += TT) csf[i] = 0.f;
  __syncthreads();
  {
    s8v av[2]; f4v rac[2] = {{},{}};
    #pragma unroll
    for (int jj = 0; jj < 2; ++jj) { int vt = wv + 16*jj; if (vt < 25) av[jj] = ld8(S + X1S + VXA(vt*16 + r, q*8)); }
    for (int wt = 0; wt < 25; ++wt) {
      s8v b = ld8(S + X2S + VXA(wt*16 + r, q*8));
      float cp = 0.f;
      #pragma unroll
      for (int jj = 0; jj < 2; ++jj) {
        int vt = wv + 16*jj;
        if (vt < 25) {
          f4v z = {}; z = MF16(av[jj], b, z);
          #pragma unroll
          for (int e = 0; e < 4; ++e) { float ev = E2(z[e]); rac[jj][e] += ev; cp += ev; }
        }
      }
      cp += __shfl_xor(cp, 16); cp += __shfl_xor(cp, 32);
      if (q == 0) atomicAdd(&csf[wt*16 + r], cp);
    }
    #pragma unroll
    for (int jj = 0; jj < 2; ++jj) {
      int vt = wv + 16*jj;
      if (vt < 25) {
        #pragma unroll
        for (int e = 0; e < 4; ++e) {
          float s = rac[jj][e];
          s += __shfl_xor(s,1); s += __shfl_xor(s,2); s += __shfl_xor(s,4); s += __shfl_xor(s,8);
          if (r == 0) rsf[vt*16 + q*4 + e] = s;
        }
      }
    }
  }
  __syncthreads();
  for (int i = t; i < 400; i += TT) { S[RINV + i] = f2bf(1.f/rsf[i]); S[CINV + i] = f2bf(1.f/csf[i]); }
  __syncthreads();

  // ---------- Diffusion: wave-private producer/consumer units, zero intra-step barriers.
  // Round-6 delta vs round-1 (single variable): the tail unit's P LDS round-trip is
  // replaced by an in-register lane exchange (8 shfl + 4 selects) — the write/read maps
  // compose to a pure intra-wave permutation: reader (q,r) takes the uint2 of lanes
  // ((2q)&3, r) and ((2q+1)&3, r), ct-half selected by q>=2. This removes ALL LDS
  // stores from the sb loop in every path, so alias fences vanish and the compiler
  // can hoist the sb-invariant b-frags + pipeline ds_reads itself (no manual arrays,
  // which spilled in rounds 2/4/5). P buffers are gone entirely. ----------
  f16v acc[2];
  for (int step = 0; step < 2; ++step) {
    { f16v zv = {}; acc[0]=zv; acc[1]=zv; }
    const uint16_t* AH = S + (step ? HCV : XCV);
    const uint16_t* AG = S + (step ? GCV : XCV);
    for (int sb = 0; sb < 13; ++sb) {
      const int vbase = sb*32;
      const bool lastsb = (sb == 12);
      const int kmax = lastsb ? 1 : 2;
      s8v fr[2][2];        // [jj][k] in-register P b-frags (main units)
      uint2 td0[2], td1[2]; // tail-unit P pieces (ct=0 / ct=1)
      // ---- T: produce this wave's P (registers in all paths) ----
      #pragma unroll
      for (int jj = 0; jj < 2; ++jj) {
        int g = wv + 16*jj;
        if (g >= 26) continue;
        int chain = (g < 13) ? 0 : 1;
        int uu = g - 13*chain;
        const uint16_t* sa = S + (chain ? X2S : X1S);   // m-operand: v-slab rows
        const uint16_t* sb2 = S + (chain ? X1S : X2S);  // n-operand: w-tile rows
        const int scl = chain ? CINV : RINV;
        if (uu < 12) {
          s8v a0 = ld8(sa + VXA(vbase + m32, h2*8));
          s8v a1 = ld8(sa + VXA(vbase + m32, 16 + h2*8));
          s8v b0 = ld8(sb2 + VXA(uu*32 + m32, h2*8));
          s8v b1 = ld8(sb2 + VXA(uu*32 + m32, 16 + h2*8));
          f16v z = {}; z = MF32(a0, b0, z); z = MF32(a1, b1, z);
          #pragma unroll
          for (int k = 0; k < 2; ++k) {
            if (k < kmax) {
              const uint16_t* spt = S + scl + vbase + 16*k + 4*h2;
              uint32_t sAB = *(const uint32_t*)(spt);
              uint32_t sCD = *(const uint32_t*)(spt + 2);
              uint32_t sEF = *(const uint32_t*)(spt + 8);
              uint32_t sGH = *(const uint32_t*)(spt + 10);
              uint32_t C0 = cvtpk(E2(z[8*k+0])*bfLO(sAB), E2(z[8*k+1])*bfHI(sAB));
              uint32_t C1 = cvtpk(E2(z[8*k+2])*bfLO(sCD), E2(z[8*k+3])*bfHI(sCD));
              uint32_t C2 = cvtpk(E2(z[8*k+4])*bfLO(sEF), E2(z[8*k+5])*bfHI(sEF));
              uint32_t C3 = cvtpk(E2(z[8*k+6])*bfLO(sGH), E2(z[8*k+7])*bfHI(sGH));
              pl32swap(C0, C2);   // C0 -> dw0, C2 -> dw2
              pl32swap(C1, C3);   // C1 -> dw1, C3 -> dw3
              union { uint32_t d[4]; s8v v8; } F;
              F.d[0] = C0; F.d[1] = C1; F.d[2] = C2; F.d[3] = C3;
              fr[jj][k] = F.v8;
            }
          }
        } else {
          // tail rows 384..399: all-register (ct=0 always; ct=1 skipped at lastsb -> zeros = old pad)
          s8v bT = ld8(sb2 + VXA(384 + r, q*8));
          td1[jj].x = 0u; td1[jj].y = 0u;
          {
            s8v a = ld8(sa + VXA(vbase + r, q*8));
            f4v z4 = {}; z4 = MF16(a, bT, z4);
            float p0 = E2(z4[0]) * bf2f(S[scl + vbase + q*4 + 0]);
            float p1 = E2(z4[1]) * bf2f(S[scl + vbase + q*4 + 1]);
            float p2 = E2(z4[2]) * bf2f(S[scl + vbase + q*4 + 2]);
            float p3 = E2(z4[3]) * bf2f(S[scl + vbase + q*4 + 3]);
            td0[jj].x = cvtpk(p0,p1); td0[jj].y = cvtpk(p2,p3);
          }
          if (!lastsb) {
            s8v a = ld8(sa + VXA(vbase + 16 + r, q*8));
            f4v z4 = {}; z4 = MF16(a, bT, z4);
            float p0 = E2(z4[0]) * bf2f(S[scl + vbase + 16 + q*4 + 0]);
            float p1 = E2(z4[1]) * bf2f(S[scl + vbase + 16 + q*4 + 1]);
            float p2 = E2(z4[2]) * bf2f(S[scl + vbase + 16 + q*4 + 2]);
            float p3 = E2(z4[3]) * bf2f(S[scl + vbase + 16 + q*4 + 3]);
            td1[jj].x = cvtpk(p0,p1); td1[jj].y = cvtpk(p2,p3);
          }
        }
      }
      // ---- GEMM: consume this wave's own P (register frags / shfl exchange) ----
      #pragma unroll
      for (int jj = 0; jj < 2; ++jj) {
        int g = wv + 16*jj;
        if (g >= 26) continue;
        int chain = (g < 13) ? 0 : 1;
        int uu = g - 13*chain;
        const uint16_t* Acv = chain ? AG : AH;
        if (uu < 12) {
          #pragma unroll
          for (int k = 0; k < 2; ++k) {
            if (k < kmax) {
              s8v a = ld8(Acv + m32*STRD + vbase + k*16 + h2*8);
              acc[jj] = MF32(a, fr[jj][k], acc[jj]);
            }
          }
        } else {
          // b-frag via lane exchange: reader (q,r) <- lanes ((2q)&3, r), ((2q+1)&3, r)
          const int src0 = (((q<<1)) & 3)*16 + r;
          const int src1 = (((q<<1)+1) & 3)*16 + r;
          uint32_t a0x = (uint32_t)__shfl((int)td0[jj].x, src0);
          uint32_t a0y = (uint32_t)__shfl((int)td0[jj].y, src0);
          uint32_t a1x = (uint32_t)__shfl((int)td1[jj].x, src0);
          uint32_t a1y = (uint32_t)__shfl((int)td1[jj].y, src0);
          uint32_t b0x = (uint32_t)__shfl((int)td0[jj].x, src1);
          uint32_t b0y = (uint32_t)__shfl((int)td0[jj].y, src1);
          uint32_t b1x = (uint32_t)__shfl((int)td1[jj].x, src1);
          uint32_t b1y = (uint32_t)__shfl((int)td1[jj].y, src1);
          const bool hi = (q >= 2);
          union { uint32_t u[4]; s8v v8; } B;
          B.u[0] = hi ? a1x : a0x;
          B.u[1] = hi ? a1y : a0y;
          B.u[2] = hi ? b1x : b0x;
          B.u[3] = hi ? b1y : b0y;
          #pragma unroll
          for (int mt2 = 0; mt2 < 2; ++mt2) {
            int koff = (lastsb && q >= 2) ? 0 : q*8;   // A pad cols garbage — redirect (B=0 there)
            s8v a = ld8(Acv + (mt2*16 + r)*STRD + vbase + koff);
            f4v c4 = { acc[jj][4*mt2+0], acc[jj][4*mt2+1], acc[jj][4*mt2+2], acc[jj][4*mt2+3] };
            c4 = MF16(a, B.v8, c4);
            acc[jj][4*mt2+0]=c4[0]; acc[jj][4*mt2+1]=c4[1]; acc[jj][4*mt2+2]=c4[2]; acc[jj][4*mt2+3]=c4[3];
          }
        }
      }
    } // sb
    __syncthreads();
    if (step == 0) {
      // epilogue: H1/G1 = AL*X + OM*acc -> HCV/GCV [c][408]
      #pragma unroll
      for (int jj = 0; jj < 2; ++jj) {
        int g = wv + 16*jj;
        if (g >= 26) continue;
        int chain = (g < 13) ? 0 : 1;
        int uu = g - 13*chain;
        uint16_t* dst = S + (chain ? GCV : HCV);
        if (uu < 12) {
          int w = uu*32 + m32;
          #pragma unroll
          for (int e2 = 0; e2 < 16; ++e2) {
            int c = ROWF(e2);
            dst[c*STRD + w] = f2bf(AL*bf2f(S[XCV + c*STRD + w]) + OM*acc[jj][e2]);
          }
        } else {
          int w = 384 + r;
          #pragma unroll
          for (int mt2 = 0; mt2 < 2; ++mt2)
            #pragma unroll
            for (int e = 0; e < 4; ++e) {
              int c = mt2*16 + q*4 + e;
              dst[c*STRD + w] = f2bf(AL*bf2f(S[XCV + c*STRD + w]) + OM*acc[jj][4*mt2+e]);
            }
        }
      }
      __syncthreads();
    }
  } // step

  // ---------- MLP prep: features to swizzled [v][32]; weights folded into HCV ----------
  for (int i = t; i < 12800; i += TT) {
    int v = i >> 5, c = i & 31;
    int d = VXA(v, c);
    S[X1S + d] = S[HCV + c*STRD + v];   // H1
    S[X2S + d] = S[GCV + c*STRD + v];   // G1
  }
  #pragma unroll
  for (int jj = 0; jj < 2; ++jj) {
    int g = wv + 16*jj;
    if (g >= 26) continue;
    int chain = (g < 13) ? 0 : 1;
    int uu = g - 13*chain;
    uint16_t* dst = S + (chain ? PBA : XCV);   // H2' -> XCV, G2' -> PBA  (as swizzled [v][32])
    if (uu < 12) {
      int w = uu*32 + m32;
      #pragma unroll
      for (int gg = 0; gg < 4; ++gg) {
        uint2 d;
        d.x = cvtpk(OM*acc[jj][4*gg+0], OM*acc[jj][4*gg+1]);
        d.y = cvtpk(OM*acc[jj][4*gg+2], OM*acc[jj][4*gg+3]);
        *(uint2*)(dst + VXA(w, 8*gg + 4*h2)) = d;
      }
    } else {
      int w = 384 + r;
      #pragma unroll
      for (int mt2 = 0; mt2 < 2; ++mt2) {
        uint2 d;
        d.x = cvtpk(OM*acc[jj][4*mt2+0], OM*acc[jj][4*mt2+1]);
        d.y = cvtpk(OM*acc[jj][4*mt2+2], OM*acc[jj][4*mt2+3]);
        *(uint2*)(dst + VXA(w, mt2*16 + q*4)) = d;
      }
    }
  }
  __syncthreads();
  for (int i = t; i < 1024; i += TT) {
    int o = i >> 5, c = i & 31;
    float h2w = wm1[o*96 + 64 + c], g2w = wm2[o*96 + 64 + c];
    S[HCV +        o*40 + c] = f2bf(wm1[o*96 + c] + wm2[o*96 + c] + AL*(h2w + g2w));
    S[HCV + 1280 + o*40 + c] = f2bf(wm1[o*96 + 32 + c]);
    S[HCV + 2560 + o*40 + c] = f2bf(h2w);
    S[HCV + 3840 + o*40 + c] = f2bf(wm2[o*96 + 32 + c]);
    S[HCV + 5120 + o*40 + c] = f2bf(g2w);
  }
  if (t < 32) ((float*)(S + HCV + 6400))[t] = bm1[t] + bm2[t];
  __syncthreads();

  // ---------- MLP + coalesced staged store to gStage[n][l][o][v] ----------
  {
    const float* boF = (const float*)(S + HCV + 6400);
    float* oSl = gStage + (long)(n*12 + l)*12800;
    const int fb[5] = { 0, X1S, XCV, X2S, PBA };   // X(regs), H1, H2', G1, G2'
    int m = wv;
    if (m < 12) {
      f16v z = {};
      #pragma unroll
      for (int p = 0; p < 5; ++p) {
        #pragma unroll
        for (int kk = 0; kk < 2; ++kk) {
          s8v a = ld8(S + HCV + p*1280 + m32*40 + kk*16 + h2*8);
          s8v b;
          if (p == 0) b = kk ? xf1 : xf0;
          else        b = ld8(S + fb[p] + VXA(m*32 + m32, kk*16 + h2*8));
          z = MF32(a, b, z);
        }
      }
      int v = m*32 + m32;
      #pragma unroll
      for (int e2 = 0; e2 < 16; ++e2) {
        int o = ROWF(e2);
        oSl[o*400 + v] = z[e2] + boF[o];
      }
    } else if (m < 14) {
      int mt = m - 12;
      f4v z4 = {};
      #pragma unroll
      for (int p = 0; p < 5; ++p) {
        s8v a = ld8(S + HCV + p*1280 + (mt*16 + r)*40 + q*8);
        s8v b = (p == 0) ? xft : ld8(S + fb[p] + VXA(384 + r, q*8));
        z4 = MF16(a, b, z4);
      }
      #pragma unroll
      for (int e = 0; e < 4; ++e) {
        int o = mt*16 + q*4 + e;
        oSl[o*400 + 384 + r] = z4[e] + boF[o];
      }
    }
  }
}

// Plain transpose kernel: gStage[n][l][o][v] -> out[n][o][v][l] (both sides coalesced)
__global__ __launch_bounds__(256) void finT(float* __restrict__ out) {
  int idx = blockIdx.x*256 + threadIdx.x;      // n*12800 + ov
  int n = idx / 12800, ov = idx - n*12800;
  const float* src = gStage + (long)n*153600 + ov;
  float vals[12];
  #pragma unroll
  for (int l = 0; l < 12; ++l) vals[l] = src[(long)l*12800];
  float4* dst = (float4*)(out + (long)idx*12);
  dst[0] = make_float4(vals[0],vals[1],vals[2],vals[3]);
  dst[1] = make_float4(vals[4],vals[5],vals[6],vals[7]);
  dst[2] = make_float4(vals[8],vals[9],vals[10],vals[11]);
}

extern "C" void kernel_launch(void* const* d_in, const int* in_sizes, int n_in,
                              void* d_out, int out_size, void* d_ws, size_t ws_size,
                              hipStream_t stream) {
  (void)in_sizes; (void)n_in; (void)out_size; (void)d_ws; (void)ws_size;
  dymix<<<dim3(384), dim3(TT), 0, stream>>>(
      (const float*)d_in[0],
      (const float*)d_in[1], (const float*)d_in[2],
      (const float*)d_in[3], (const float*)d_in[4],
      (const float*)d_in[5], (const float*)d_in[6],
      (const float*)d_in[7], (const float*)d_in[8]);
  finT<<<dim3(1600), dim3(256), 0, stream>>>((float*)d_out);
}